// Round 8
// baseline (226.260 us; speedup 1.0000x reference)
//
#include <hip/hip_runtime.h>
#include <hip/hip_fp16.h>

#define N_NODES 100000
#define N_EDGES 1600000
#define D_IN 128
#define D_OUT 64
#define NB 391          // ceil(100000/256) buckets of 256 dst nodes
#define EPB 4096        // edges per block in bhist/part
#define NPART 391       // ceil(1600000/4096)
#define BKT_CAP 4864    // max edges per bucket (mean 4096, sigma ~64 -> 12 sigma)

// ws layout (4B units):
//   counts int[N] | dinv f[N] | hs16 half[N*64] (=N*32 dwords) | part int[E] |
//   bsum int[392] | eoff int[392] | ecur int[391] | noff int[N]

// Per-block LDS bucket histogram -> few global atomics (391/block max).
__global__ __launch_bounds__(256) void k_bhist(const int* __restrict__ dst,
                                               int* __restrict__ bcnt) {
    __shared__ int lh[NB];
    const int t = threadIdx.x;
    const int e0 = blockIdx.x * EPB;
    for (int i = t; i < NB; i += 256) lh[i] = 0;
    __syncthreads();
#pragma unroll
    for (int i = 0; i < 16; i++) {
        int e = e0 + i * 256 + t;
        if (e < N_EDGES) atomicAdd(&lh[dst[e] >> 8], 1);
    }
    __syncthreads();
    for (int i = t; i < NB; i += 256) {
        int c = lh[i];
        if (c) atomicAdd(&bcnt[i], c);
    }
}

// Single block: exclusive scan of 391 bucket sums.
__global__ __launch_bounds__(512) void k_bscan(const int* __restrict__ bsum,
                                               int* __restrict__ eoff,
                                               int* __restrict__ ecur) {
    __shared__ int s[512];
    int t = threadIdx.x;
    int v = (t < NB) ? bsum[t] : 0;
    s[t] = v;
    __syncthreads();
    for (int d = 1; d < 512; d <<= 1) {
        int u = (t >= d) ? s[t - d] : 0;
        __syncthreads();
        s[t] += u;
        __syncthreads();
    }
    if (t < NB) {
        int excl = s[t] - v;
        eoff[t] = excl;
        ecur[t] = excl;
        if (t == NB - 1) eoff[NB] = s[t];
    }
}

// LDS-staged bucket partition: packed = (src<<8)|(dst&255), grouped by dst>>8.
__global__ __launch_bounds__(256) void k_part(const int* __restrict__ src,
                                              const int* __restrict__ dst,
                                              int* __restrict__ ecur,
                                              int* __restrict__ part) {
    __shared__ int lh[NB];
    __shared__ int lbase[NB + 1];
    __shared__ int ldelta[NB];
    __shared__ int lcur[NB];
    __shared__ int stage[EPB];
    __shared__ unsigned short sbk[EPB];
    const int t = threadIdx.x;
    const int e0 = blockIdx.x * EPB;
    for (int i = t; i < NB; i += 256) lh[i] = 0;
    __syncthreads();
    int p[16];
    short bk[16];
#pragma unroll
    for (int i = 0; i < 16; i++) {
        int e = e0 + i * 256 + t;
        bk[i] = -1;
        p[i] = 0;
        if (e < N_EDGES) {
            int s = src[e], d = dst[e];
            int b = d >> 8;
            bk[i] = (short)b;
            p[i] = (s << 8) | (d & 255);
            atomicAdd(&lh[b], 1);
        }
    }
    __syncthreads();
    // exclusive scan of lh[0..NB) by wave 0 (7 counters per lane)
    if (t < 64) {
        int c[7];
        int tot = 0;
#pragma unroll
        for (int j = 0; j < 7; j++) {
            int idx = t * 7 + j;
            c[j] = (idx < NB) ? lh[idx] : 0;
            tot += c[j];
        }
        int v = tot;
#pragma unroll
        for (int d = 1; d < 64; d <<= 1) {
            int u = __shfl_up(v, d);
            if (t >= d) v += u;
        }
        int run = v - tot;
#pragma unroll
        for (int j = 0; j < 7; j++) {
            int idx = t * 7 + j;
            if (idx < NB) lbase[idx] = run;
            run += c[j];
        }
        if (t == 63) lbase[NB] = run;  // total valid edges this block
    }
    __syncthreads();
    for (int i = t; i < NB; i += 256) {
        int cnt = lh[i];
        lcur[i] = lbase[i];
        if (cnt > 0) {
            int g = atomicAdd(&ecur[i], cnt);
            ldelta[i] = g - lbase[i];
        }
    }
    __syncthreads();
#pragma unroll
    for (int i = 0; i < 16; i++) {
        if (bk[i] >= 0) {
            int slot = atomicAdd(&lcur[bk[i]], 1);
            stage[slot] = p[i];
            sbk[slot] = (unsigned short)bk[i];
        }
    }
    __syncthreads();
    int nval = lbase[NB];
    for (int s = t; s < nval; s += 256) {
        part[ldelta[sbk[s]] + s] = stage[s];
    }
}

// One block per bucket: counting sort by dst low byte. Rewrites part[beg..end)
// in place as sorted src values; emits noff/counts/dinv per node (coalesced).
__global__ __launch_bounds__(256) void k_sort(const int* __restrict__ eoff,
                                              int* __restrict__ part,
                                              int* __restrict__ noff,
                                              int* __restrict__ counts,
                                              float* __restrict__ dinv) {
    __shared__ int lcnt[256], lcur[256];
    __shared__ int wsum[4];
    __shared__ int stage[BKT_CAP];
    const int t = threadIdx.x, b = blockIdx.x;
    const int beg = eoff[b], end = eoff[b + 1];
    const int m = end - beg;
    lcnt[t] = 0;
    __syncthreads();
    for (int i = t; i < m; i += 256) atomicAdd(&lcnt[part[beg + i] & 255], 1);
    __syncthreads();
    // exclusive scan of 256 counters
    int c = lcnt[t];
    int v = c;
    int lane = t & 63, w = t >> 6;
#pragma unroll
    for (int d = 1; d < 64; d <<= 1) {
        int u = __shfl_up(v, d);
        if (lane >= d) v += u;
    }
    if (lane == 63) wsum[w] = v;
    __syncthreads();
    int woff = 0;
#pragma unroll
    for (int k = 0; k < 4; k++) woff += (k < w) ? wsum[k] : 0;
    int excl = woff + v - c;
    lcur[t] = excl;
    int node = b * 256 + t;
    if (node < N_NODES) {
        noff[node] = beg + excl;
        counts[node] = c;
        dinv[node] = rsqrtf((float)c + 1.0f);
    }
    __syncthreads();
    for (int i = t; i < m; i += 256) {
        int pk = part[beg + i];
        int slot = atomicAdd(&lcur[pk & 255], 1);
        stage[slot] = pk >> 8;  // unpack src
    }
    __syncthreads();
    for (int i = t; i < m; i += 256) part[beg + i] = stage[i];
}

// GEMM: 16 rows/block (4 rows per wave), lane = output column.
// hs16 = fp16((x@w) * dinv[row]).
__global__ __launch_bounds__(256) void k_gemm(const float* __restrict__ x,
                                              const float* __restrict__ w,
                                              const float* __restrict__ dinv,
                                              __half* __restrict__ hs16) {
    __shared__ float wl[D_IN * D_OUT];  // 32 KB
    __shared__ float xl[16][D_IN];      // 8 KB
    const int t = threadIdx.x;
    for (int i = t; i < D_IN * D_OUT; i += 256) wl[i] = w[i];
    const int row0 = blockIdx.x * 16;
    const float4* xg = (const float4*)(x + (size_t)row0 * D_IN);
    float4* xs = (float4*)&xl[0][0];
    xs[t]       = xg[t];
    xs[t + 256] = xg[t + 256];
    __syncthreads();

    const int wave = t >> 6, lane = t & 63;
    const int r0 = wave * 4;
    float acc0 = 0.f, acc1 = 0.f, acc2 = 0.f, acc3 = 0.f;
#pragma unroll
    for (int k0 = 0; k0 < D_IN; k0 += 4) {
        float4 x0 = *(const float4*)&xl[r0 + 0][k0];
        float4 x1 = *(const float4*)&xl[r0 + 1][k0];
        float4 x2 = *(const float4*)&xl[r0 + 2][k0];
        float4 x3 = *(const float4*)&xl[r0 + 3][k0];
        float w0 = wl[(k0 + 0) * 64 + lane];
        float w1 = wl[(k0 + 1) * 64 + lane];
        float w2 = wl[(k0 + 2) * 64 + lane];
        float w3 = wl[(k0 + 3) * 64 + lane];
        acc0 = fmaf(x0.w, w3, fmaf(x0.z, w2, fmaf(x0.y, w1, fmaf(x0.x, w0, acc0))));
        acc1 = fmaf(x1.w, w3, fmaf(x1.z, w2, fmaf(x1.y, w1, fmaf(x1.x, w0, acc1))));
        acc2 = fmaf(x2.w, w3, fmaf(x2.z, w2, fmaf(x2.y, w1, fmaf(x2.x, w0, acc2))));
        acc3 = fmaf(x3.w, w3, fmaf(x3.z, w2, fmaf(x3.y, w1, fmaf(x3.x, w0, acc3))));
    }
    const int gr = row0 + r0;
    hs16[(size_t)(gr + 0) * 64 + lane] = __float2half(acc0 * dinv[gr + 0]);
    hs16[(size_t)(gr + 1) * 64 + lane] = __float2half(acc1 * dinv[gr + 1]);
    hs16[(size_t)(gr + 2) * 64 + lane] = __float2half(acc2 * dinv[gr + 2]);
    hs16[(size_t)(gr + 3) * 64 + lane] = __float2half(acc3 * dinv[gr + 3]);
}

// One wave per node; wave splits into two 32-lane halves, each half processes
// its own edge (per-lane __shfl source), lane covers 2 columns as __half2.
// fp32 accumulate, cross-half shfl_xor reduce, fused epilogue.
__global__ __launch_bounds__(256) void k_agg(const int* __restrict__ noff,
                                             const int* __restrict__ counts,
                                             const int* __restrict__ ssrc,
                                             const float* __restrict__ dinv,
                                             const __half2* __restrict__ hs2,
                                             const float* __restrict__ bias,
                                             float* __restrict__ out) {
    int t = blockIdx.x * 256 + threadIdx.x;
    int node = t >> 6, lane = t & 63;
    if (node >= N_NODES) return;
    const int half = lane >> 5;   // which edge of the pair
    const int hl = lane & 31;     // half2 column index (cols 2*hl, 2*hl+1)
    int beg = noff[node];
    int cnt = counts[node];
    float ax0 = 0.f, ay0 = 0.f, ax1 = 0.f, ay1 = 0.f;
    float ax2 = 0.f, ay2 = 0.f, ax3 = 0.f, ay3 = 0.f;
    for (int base = 0; base < cnt; base += 64) {
        int m = min(64, cnt - base);
        int sl = (base + lane < cnt) ? ssrc[beg + base + lane] : 0;
        if (m == 64) {
#pragma unroll
            for (int k = 0; k < 64; k += 8) {
                int sA = __shfl(sl, k + 0 + half);
                int sB = __shfl(sl, k + 2 + half);
                int sC = __shfl(sl, k + 4 + half);
                int sD = __shfl(sl, k + 6 + half);
                float2 fA = __half22float2(hs2[((unsigned)sA << 5) + hl]);
                float2 fB = __half22float2(hs2[((unsigned)sB << 5) + hl]);
                float2 fC = __half22float2(hs2[((unsigned)sC << 5) + hl]);
                float2 fD = __half22float2(hs2[((unsigned)sD << 5) + hl]);
                ax0 += fA.x; ay0 += fA.y;
                ax1 += fB.x; ay1 += fB.y;
                ax2 += fC.x; ay2 += fC.y;
                ax3 += fD.x; ay3 += fD.y;
            }
        } else {
            for (int k = 0; k < m; k += 2) {
                int s = __shfl(sl, k + half);
                float2 f = __half22float2(hs2[((unsigned)s << 5) + hl]);
                if (k + half < m) { ax0 += f.x; ay0 += f.y; }
            }
        }
    }
    float Ax = (ax0 + ax1) + (ax2 + ax3);
    float Ay = (ay0 + ay1) + (ay2 + ay3);
    Ax += __shfl_xor(Ax, 32);
    Ay += __shfl_xor(Ay, 32);
    float2 selfv = __half22float2(hs2[((unsigned)node << 5) + hl]);
    float dv = dinv[node];
    float2 bb = ((const float2*)bias)[hl];
    float vx = dv * (Ax + selfv.x) + bb.x;
    float vy = dv * (Ay + selfv.y) + bb.y;
    vx = vx > 0.f ? vx : 0.f;
    vy = vy > 0.f ? vy : 0.f;
    if (half == 0) {
        ((float2*)out)[((unsigned)node << 5) + hl] = make_float2(vx, vy);
    }
}

extern "C" void kernel_launch(void* const* d_in, const int* in_sizes, int n_in,
                              void* d_out, int out_size, void* d_ws, size_t ws_size,
                              hipStream_t stream) {
    const float* x    = (const float*)d_in[0];
    const int*   ei   = (const int*)d_in[1];   // [2][E] row-major
    const float* w    = (const float*)d_in[2];
    const float* bias = (const float*)d_in[3];
    float* out = (float*)d_out;

    int*    counts = (int*)d_ws;                         // N
    float*  dinv   = (float*)(counts + N_NODES);         // N
    __half* hs16   = (__half*)(dinv + N_NODES);          // N*64 halves = N*32 dwords
    int*    part   = (int*)((int*)(dinv + N_NODES) + N_NODES * 32);  // E
    int*    bsum   = part + N_EDGES;                     // 392
    int*    eoff   = bsum + 392;                         // NB+1
    int*    ecur   = eoff + 392;                         // NB
    int*    noff   = ecur + NB;                          // N

    const int* srcI = ei;
    const int* dstI = ei + N_EDGES;

    hipMemsetAsync(bsum, 0, NB * sizeof(int), stream);
    hipLaunchKernelGGL(k_bhist, dim3(NPART), dim3(256), 0, stream, dstI, bsum);
    hipLaunchKernelGGL(k_bscan, dim3(1), dim3(512), 0, stream, bsum, eoff, ecur);
    hipLaunchKernelGGL(k_part, dim3(NPART), dim3(256), 0, stream, srcI, dstI, ecur, part);
    hipLaunchKernelGGL(k_sort, dim3(NB), dim3(256), 0, stream, eoff, part, noff, counts, dinv);
    hipLaunchKernelGGL(k_gemm, dim3(N_NODES / 16), dim3(256), 0, stream, x, w, dinv, hs16);
    hipLaunchKernelGGL(k_agg, dim3((N_NODES * 64) / 256), dim3(256), 0, stream,
                       noff, counts, part, dinv, (const __half2*)hs16, bias, out);
}

// Round 9
// 142.635 us; speedup vs baseline: 1.5863x; 1.5863x over previous
//
#include <hip/hip_runtime.h>
#include <hip/hip_fp16.h>

#define N_NODES 100000
#define N_EDGES 1600000
#define D_IN 128
#define D_OUT 64
#define NB 391          // ceil(100000/256) buckets of 256 dst nodes
#define EPB 4096        // edges per block in bhist/part
#define NPART 391       // ceil(1600000/4096)
#define BKT_CAP 4864    // max edges per bucket (mean 4096, sigma ~64 -> 12 sigma)

// ws layout (4B units):
//   counts int[N] | dinv f[N] | hs16 half[N*64] (=N*32 dwords) | part int[E] |
//   bsum int[392] | eoff int[392] | ecur int[391] | noff int[N]

// Per-block LDS bucket histogram -> few global atomics (391/block max).
__global__ __launch_bounds__(256) void k_bhist(const int* __restrict__ dst,
                                               int* __restrict__ bcnt) {
    __shared__ int lh[NB];
    const int t = threadIdx.x;
    const int e0 = blockIdx.x * EPB;
    for (int i = t; i < NB; i += 256) lh[i] = 0;
    __syncthreads();
#pragma unroll
    for (int i = 0; i < 16; i++) {
        int e = e0 + i * 256 + t;
        if (e < N_EDGES) atomicAdd(&lh[dst[e] >> 8], 1);
    }
    __syncthreads();
    for (int i = t; i < NB; i += 256) {
        int c = lh[i];
        if (c) atomicAdd(&bcnt[i], c);
    }
}

// Single block: exclusive scan of 391 bucket sums.
__global__ __launch_bounds__(512) void k_bscan(const int* __restrict__ bsum,
                                               int* __restrict__ eoff,
                                               int* __restrict__ ecur) {
    __shared__ int s[512];
    int t = threadIdx.x;
    int v = (t < NB) ? bsum[t] : 0;
    s[t] = v;
    __syncthreads();
    for (int d = 1; d < 512; d <<= 1) {
        int u = (t >= d) ? s[t - d] : 0;
        __syncthreads();
        s[t] += u;
        __syncthreads();
    }
    if (t < NB) {
        int excl = s[t] - v;
        eoff[t] = excl;
        ecur[t] = excl;
        if (t == NB - 1) eoff[NB] = s[t];
    }
}

// LDS-staged bucket partition: packed = (src<<8)|(dst&255), grouped by dst>>8.
__global__ __launch_bounds__(256) void k_part(const int* __restrict__ src,
                                              const int* __restrict__ dst,
                                              int* __restrict__ ecur,
                                              int* __restrict__ part) {
    __shared__ int lh[NB];
    __shared__ int lbase[NB + 1];
    __shared__ int ldelta[NB];
    __shared__ int lcur[NB];
    __shared__ int stage[EPB];
    __shared__ unsigned short sbk[EPB];
    const int t = threadIdx.x;
    const int e0 = blockIdx.x * EPB;
    for (int i = t; i < NB; i += 256) lh[i] = 0;
    __syncthreads();
    int p[16];
    short bk[16];
#pragma unroll
    for (int i = 0; i < 16; i++) {
        int e = e0 + i * 256 + t;
        bk[i] = -1;
        p[i] = 0;
        if (e < N_EDGES) {
            int s = src[e], d = dst[e];
            int b = d >> 8;
            bk[i] = (short)b;
            p[i] = (s << 8) | (d & 255);
            atomicAdd(&lh[b], 1);
        }
    }
    __syncthreads();
    // exclusive scan of lh[0..NB) by wave 0 (7 counters per lane)
    if (t < 64) {
        int c[7];
        int tot = 0;
#pragma unroll
        for (int j = 0; j < 7; j++) {
            int idx = t * 7 + j;
            c[j] = (idx < NB) ? lh[idx] : 0;
            tot += c[j];
        }
        int v = tot;
#pragma unroll
        for (int d = 1; d < 64; d <<= 1) {
            int u = __shfl_up(v, d);
            if (t >= d) v += u;
        }
        int run = v - tot;
#pragma unroll
        for (int j = 0; j < 7; j++) {
            int idx = t * 7 + j;
            if (idx < NB) lbase[idx] = run;
            run += c[j];
        }
        if (t == 63) lbase[NB] = run;  // total valid edges this block
    }
    __syncthreads();
    for (int i = t; i < NB; i += 256) {
        int cnt = lh[i];
        lcur[i] = lbase[i];
        if (cnt > 0) {
            int g = atomicAdd(&ecur[i], cnt);
            ldelta[i] = g - lbase[i];
        }
    }
    __syncthreads();
#pragma unroll
    for (int i = 0; i < 16; i++) {
        if (bk[i] >= 0) {
            int slot = atomicAdd(&lcur[bk[i]], 1);
            stage[slot] = p[i];
            sbk[slot] = (unsigned short)bk[i];
        }
    }
    __syncthreads();
    int nval = lbase[NB];
    for (int s = t; s < nval; s += 256) {
        part[ldelta[sbk[s]] + s] = stage[s];
    }
}

// One block per bucket: counting sort by dst low byte. Rewrites part[beg..end)
// in place as sorted src values; emits noff/counts/dinv per node (coalesced).
__global__ __launch_bounds__(256) void k_sort(const int* __restrict__ eoff,
                                              int* __restrict__ part,
                                              int* __restrict__ noff,
                                              int* __restrict__ counts,
                                              float* __restrict__ dinv) {
    __shared__ int lcnt[256], lcur[256];
    __shared__ int wsum[4];
    __shared__ int stage[BKT_CAP];
    const int t = threadIdx.x, b = blockIdx.x;
    const int beg = eoff[b], end = eoff[b + 1];
    const int m = end - beg;
    lcnt[t] = 0;
    __syncthreads();
    for (int i = t; i < m; i += 256) atomicAdd(&lcnt[part[beg + i] & 255], 1);
    __syncthreads();
    // exclusive scan of 256 counters
    int c = lcnt[t];
    int v = c;
    int lane = t & 63, w = t >> 6;
#pragma unroll
    for (int d = 1; d < 64; d <<= 1) {
        int u = __shfl_up(v, d);
        if (lane >= d) v += u;
    }
    if (lane == 63) wsum[w] = v;
    __syncthreads();
    int woff = 0;
#pragma unroll
    for (int k = 0; k < 4; k++) woff += (k < w) ? wsum[k] : 0;
    int excl = woff + v - c;
    lcur[t] = excl;
    int node = b * 256 + t;
    if (node < N_NODES) {
        noff[node] = beg + excl;
        counts[node] = c;
        dinv[node] = rsqrtf((float)c + 1.0f);
    }
    __syncthreads();
    for (int i = t; i < m; i += 256) {
        int pk = part[beg + i];
        int slot = atomicAdd(&lcur[pk & 255], 1);
        stage[slot] = pk >> 8;  // unpack src
    }
    __syncthreads();
    for (int i = t; i < m; i += 256) part[beg + i] = stage[i];
}

// GEMM: 16 rows/block (4 rows per wave), lane = output column.
// hs16 = fp16((x@w) * dinv[row]).
__global__ __launch_bounds__(256) void k_gemm(const float* __restrict__ x,
                                              const float* __restrict__ w,
                                              const float* __restrict__ dinv,
                                              __half* __restrict__ hs16) {
    __shared__ float wl[D_IN * D_OUT];  // 32 KB
    __shared__ float xl[16][D_IN];      // 8 KB
    const int t = threadIdx.x;
    for (int i = t; i < D_IN * D_OUT; i += 256) wl[i] = w[i];
    const int row0 = blockIdx.x * 16;
    const float4* xg = (const float4*)(x + (size_t)row0 * D_IN);
    float4* xs = (float4*)&xl[0][0];
    xs[t]       = xg[t];
    xs[t + 256] = xg[t + 256];
    __syncthreads();

    const int wave = t >> 6, lane = t & 63;
    const int r0 = wave * 4;
    float acc0 = 0.f, acc1 = 0.f, acc2 = 0.f, acc3 = 0.f;
#pragma unroll
    for (int k0 = 0; k0 < D_IN; k0 += 4) {
        float4 x0 = *(const float4*)&xl[r0 + 0][k0];
        float4 x1 = *(const float4*)&xl[r0 + 1][k0];
        float4 x2 = *(const float4*)&xl[r0 + 2][k0];
        float4 x3 = *(const float4*)&xl[r0 + 3][k0];
        float w0 = wl[(k0 + 0) * 64 + lane];
        float w1 = wl[(k0 + 1) * 64 + lane];
        float w2 = wl[(k0 + 2) * 64 + lane];
        float w3 = wl[(k0 + 3) * 64 + lane];
        acc0 = fmaf(x0.w, w3, fmaf(x0.z, w2, fmaf(x0.y, w1, fmaf(x0.x, w0, acc0))));
        acc1 = fmaf(x1.w, w3, fmaf(x1.z, w2, fmaf(x1.y, w1, fmaf(x1.x, w0, acc1))));
        acc2 = fmaf(x2.w, w3, fmaf(x2.z, w2, fmaf(x2.y, w1, fmaf(x2.x, w0, acc2))));
        acc3 = fmaf(x3.w, w3, fmaf(x3.z, w2, fmaf(x3.y, w1, fmaf(x3.x, w0, acc3))));
    }
    const int gr = row0 + r0;
    hs16[(size_t)(gr + 0) * 64 + lane] = __float2half(acc0 * dinv[gr + 0]);
    hs16[(size_t)(gr + 1) * 64 + lane] = __float2half(acc1 * dinv[gr + 1]);
    hs16[(size_t)(gr + 2) * 64 + lane] = __float2half(acc2 * dinv[gr + 2]);
    hs16[(size_t)(gr + 3) * 64 + lane] = __float2half(acc3 * dinv[gr + 3]);
}

// One wave per node. Src indices are wave-uniform -> scalar (s_load) reads,
// no cross-lane ops. Each lane covers 2 columns (__half2, 4B load); the two
// 32-lane halves take the even/odd edge of each pair -> 256B per wave-load.
// fp32 accumulate, one shfl_xor(32) pair at the end, fused epilogue.
__global__ __launch_bounds__(256) void k_agg(const int* __restrict__ noff,
                                             const int* __restrict__ counts,
                                             const int* __restrict__ ssrc,
                                             const float* __restrict__ dinv,
                                             const __half2* __restrict__ hs2,
                                             const float* __restrict__ bias,
                                             float* __restrict__ out) {
    int t = blockIdx.x * 256 + threadIdx.x;
    int node = t >> 6, lane = t & 63;
    if (node >= N_NODES) return;
    const int half = lane >> 5;   // which edge of the pair
    const int hl = lane & 31;     // half2 column index (cols 2*hl, 2*hl+1)
    const int beg = __builtin_amdgcn_readfirstlane(noff[node]);
    const int cnt = __builtin_amdgcn_readfirstlane(counts[node]);
    float ax0 = 0.f, ay0 = 0.f, ax1 = 0.f, ay1 = 0.f;
    float ax2 = 0.f, ay2 = 0.f, ax3 = 0.f, ay3 = 0.f;
    int k = 0;
    for (; k + 8 <= cnt; k += 8) {
        int r0a = ssrc[beg + k + 0], r0b = ssrc[beg + k + 1];
        int r1a = ssrc[beg + k + 2], r1b = ssrc[beg + k + 3];
        int r2a = ssrc[beg + k + 4], r2b = ssrc[beg + k + 5];
        int r3a = ssrc[beg + k + 6], r3b = ssrc[beg + k + 7];
        int r0 = half ? r0b : r0a;
        int r1 = half ? r1b : r1a;
        int r2 = half ? r2b : r2a;
        int r3 = half ? r3b : r3a;
        float2 f0 = __half22float2(hs2[((unsigned)r0 << 5) + hl]);
        float2 f1 = __half22float2(hs2[((unsigned)r1 << 5) + hl]);
        float2 f2 = __half22float2(hs2[((unsigned)r2 << 5) + hl]);
        float2 f3 = __half22float2(hs2[((unsigned)r3 << 5) + hl]);
        ax0 += f0.x; ay0 += f0.y;
        ax1 += f1.x; ay1 += f1.y;
        ax2 += f2.x; ay2 += f2.y;
        ax3 += f3.x; ay3 += f3.y;
    }
    for (; k < cnt; k += 2) {
        int ra = ssrc[beg + k];
        int rb = (k + 1 < cnt) ? ssrc[beg + k + 1] : ra;
        int r = half ? rb : ra;
        float2 f = __half22float2(hs2[((unsigned)r << 5) + hl]);
        // when pair is incomplete, half 1 would duplicate edge ra -> mask it
        if (half == 0 || k + 1 < cnt) { ax0 += f.x; ay0 += f.y; }
    }
    float Ax = (ax0 + ax1) + (ax2 + ax3);
    float Ay = (ay0 + ay1) + (ay2 + ay3);
    Ax += __shfl_xor(Ax, 32);
    Ay += __shfl_xor(Ay, 32);
    float2 selfv = __half22float2(hs2[((unsigned)node << 5) + hl]);
    float dv = dinv[node];
    float2 bb = ((const float2*)bias)[hl];
    float vx = dv * (Ax + selfv.x) + bb.x;
    float vy = dv * (Ay + selfv.y) + bb.y;
    vx = vx > 0.f ? vx : 0.f;
    vy = vy > 0.f ? vy : 0.f;
    if (half == 0) {
        ((float2*)out)[((unsigned)node << 5) + hl] = make_float2(vx, vy);
    }
}

extern "C" void kernel_launch(void* const* d_in, const int* in_sizes, int n_in,
                              void* d_out, int out_size, void* d_ws, size_t ws_size,
                              hipStream_t stream) {
    const float* x    = (const float*)d_in[0];
    const int*   ei   = (const int*)d_in[1];   // [2][E] row-major
    const float* w    = (const float*)d_in[2];
    const float* bias = (const float*)d_in[3];
    float* out = (float*)d_out;

    int*    counts = (int*)d_ws;                         // N
    float*  dinv   = (float*)(counts + N_NODES);         // N
    __half* hs16   = (__half*)(dinv + N_NODES);          // N*64 halves = N*32 dwords
    int*    part   = (int*)((int*)(dinv + N_NODES) + N_NODES * 32);  // E
    int*    bsum   = part + N_EDGES;                     // 392
    int*    eoff   = bsum + 392;                         // NB+1
    int*    ecur   = eoff + 392;                         // NB
    int*    noff   = ecur + NB;                          // N

    const int* srcI = ei;
    const int* dstI = ei + N_EDGES;

    hipMemsetAsync(bsum, 0, NB * sizeof(int), stream);
    hipLaunchKernelGGL(k_bhist, dim3(NPART), dim3(256), 0, stream, dstI, bsum);
    hipLaunchKernelGGL(k_bscan, dim3(1), dim3(512), 0, stream, bsum, eoff, ecur);
    hipLaunchKernelGGL(k_part, dim3(NPART), dim3(256), 0, stream, srcI, dstI, ecur, part);
    hipLaunchKernelGGL(k_sort, dim3(NB), dim3(256), 0, stream, eoff, part, noff, counts, dinv);
    hipLaunchKernelGGL(k_gemm, dim3(N_NODES / 16), dim3(256), 0, stream, x, w, dinv, hs16);
    hipLaunchKernelGGL(k_agg, dim3((N_NODES * 64) / 256), dim3(256), 0, stream,
                       noff, counts, part, dinv, (const __half2*)hs16, bias, out);
}

// Round 10
// 115.015 us; speedup vs baseline: 1.9672x; 1.2401x over previous
//
#include <hip/hip_runtime.h>
#include <hip/hip_fp16.h>

#define N_NODES 100000
#define N_EDGES 1600000
#define D_IN 128
#define D_OUT 64
#define NB 391          // ceil(100000/256) buckets of 256 dst nodes
#define EPB 4096        // edges per block in bhist/part
#define NPART 391       // ceil(1600000/4096)
#define BKT_CAP 4864    // max edges per bucket (mean 4096, sigma ~64 -> 12 sigma)

typedef _Float16 f16x8 __attribute__((ext_vector_type(8)));
typedef float f32x4 __attribute__((ext_vector_type(4)));

// ws layout (4B units):
//   counts int[N] | dinv f[N] | hs16 half[N*64] (=N*32 dwords) | part int[E] |
//   bsum int[392] | eoff int[392] | ecur int[391] | noff int[N]

// Per-block LDS bucket histogram -> few global atomics (391/block max).
__global__ __launch_bounds__(256) void k_bhist(const int* __restrict__ dst,
                                               int* __restrict__ bcnt) {
    __shared__ int lh[NB];
    const int t = threadIdx.x;
    const int e0 = blockIdx.x * EPB;
    for (int i = t; i < NB; i += 256) lh[i] = 0;
    __syncthreads();
#pragma unroll
    for (int i = 0; i < 16; i++) {
        int e = e0 + i * 256 + t;
        if (e < N_EDGES) atomicAdd(&lh[dst[e] >> 8], 1);
    }
    __syncthreads();
    for (int i = t; i < NB; i += 256) {
        int c = lh[i];
        if (c) atomicAdd(&bcnt[i], c);
    }
}

// Single block: exclusive scan of 391 bucket sums.
__global__ __launch_bounds__(512) void k_bscan(const int* __restrict__ bsum,
                                               int* __restrict__ eoff,
                                               int* __restrict__ ecur) {
    __shared__ int s[512];
    int t = threadIdx.x;
    int v = (t < NB) ? bsum[t] : 0;
    s[t] = v;
    __syncthreads();
    for (int d = 1; d < 512; d <<= 1) {
        int u = (t >= d) ? s[t - d] : 0;
        __syncthreads();
        s[t] += u;
        __syncthreads();
    }
    if (t < NB) {
        int excl = s[t] - v;
        eoff[t] = excl;
        ecur[t] = excl;
        if (t == NB - 1) eoff[NB] = s[t];
    }
}

// LDS-staged bucket partition: packed = (src<<8)|(dst&255), grouped by dst>>8.
__global__ __launch_bounds__(256) void k_part(const int* __restrict__ src,
                                              const int* __restrict__ dst,
                                              int* __restrict__ ecur,
                                              int* __restrict__ part) {
    __shared__ int lh[NB];
    __shared__ int lbase[NB + 1];
    __shared__ int ldelta[NB];
    __shared__ int lcur[NB];
    __shared__ int stage[EPB];
    __shared__ unsigned short sbk[EPB];
    const int t = threadIdx.x;
    const int e0 = blockIdx.x * EPB;
    for (int i = t; i < NB; i += 256) lh[i] = 0;
    __syncthreads();
    int p[16];
    short bk[16];
#pragma unroll
    for (int i = 0; i < 16; i++) {
        int e = e0 + i * 256 + t;
        bk[i] = -1;
        p[i] = 0;
        if (e < N_EDGES) {
            int s = src[e], d = dst[e];
            int b = d >> 8;
            bk[i] = (short)b;
            p[i] = (s << 8) | (d & 255);
            atomicAdd(&lh[b], 1);
        }
    }
    __syncthreads();
    // exclusive scan of lh[0..NB) by wave 0 (7 counters per lane)
    if (t < 64) {
        int c[7];
        int tot = 0;
#pragma unroll
        for (int j = 0; j < 7; j++) {
            int idx = t * 7 + j;
            c[j] = (idx < NB) ? lh[idx] : 0;
            tot += c[j];
        }
        int v = tot;
#pragma unroll
        for (int d = 1; d < 64; d <<= 1) {
            int u = __shfl_up(v, d);
            if (t >= d) v += u;
        }
        int run = v - tot;
#pragma unroll
        for (int j = 0; j < 7; j++) {
            int idx = t * 7 + j;
            if (idx < NB) lbase[idx] = run;
            run += c[j];
        }
        if (t == 63) lbase[NB] = run;  // total valid edges this block
    }
    __syncthreads();
    for (int i = t; i < NB; i += 256) {
        int cnt = lh[i];
        lcur[i] = lbase[i];
        if (cnt > 0) {
            int g = atomicAdd(&ecur[i], cnt);
            ldelta[i] = g - lbase[i];
        }
    }
    __syncthreads();
#pragma unroll
    for (int i = 0; i < 16; i++) {
        if (bk[i] >= 0) {
            int slot = atomicAdd(&lcur[bk[i]], 1);
            stage[slot] = p[i];
            sbk[slot] = (unsigned short)bk[i];
        }
    }
    __syncthreads();
    int nval = lbase[NB];
    for (int s = t; s < nval; s += 256) {
        part[ldelta[sbk[s]] + s] = stage[s];
    }
}

// One block per bucket: counting sort by dst low byte. Rewrites part[beg..end)
// in place as sorted src values; emits noff/counts/dinv per node (coalesced).
__global__ __launch_bounds__(256) void k_sort(const int* __restrict__ eoff,
                                              int* __restrict__ part,
                                              int* __restrict__ noff,
                                              int* __restrict__ counts,
                                              float* __restrict__ dinv) {
    __shared__ int lcnt[256], lcur[256];
    __shared__ int wsum[4];
    __shared__ int stage[BKT_CAP];
    const int t = threadIdx.x, b = blockIdx.x;
    const int beg = eoff[b], end = eoff[b + 1];
    const int m = end - beg;
    lcnt[t] = 0;
    __syncthreads();
    for (int i = t; i < m; i += 256) atomicAdd(&lcnt[part[beg + i] & 255], 1);
    __syncthreads();
    // exclusive scan of 256 counters
    int c = lcnt[t];
    int v = c;
    int lane = t & 63, w = t >> 6;
#pragma unroll
    for (int d = 1; d < 64; d <<= 1) {
        int u = __shfl_up(v, d);
        if (lane >= d) v += u;
    }
    if (lane == 63) wsum[w] = v;
    __syncthreads();
    int woff = 0;
#pragma unroll
    for (int k = 0; k < 4; k++) woff += (k < w) ? wsum[k] : 0;
    int excl = woff + v - c;
    lcur[t] = excl;
    int node = b * 256 + t;
    if (node < N_NODES) {
        noff[node] = beg + excl;
        counts[node] = c;
        dinv[node] = rsqrtf((float)c + 1.0f);
    }
    __syncthreads();
    for (int i = t; i < m; i += 256) {
        int pk = part[beg + i];
        int slot = atomicAdd(&lcur[pk & 255], 1);
        stage[slot] = pk >> 8;  // unpack src
    }
    __syncthreads();
    for (int i = t; i < m; i += 256) part[beg + i] = stage[i];
}

// MFMA f16 GEMM: 64 rows x 64 cols per block (4 waves). x,w converted to fp16
// during LDS staging, stored in MFMA fragment order ([lane][8] halves, 16B/lane
// -> conflict-free ds_read_b128). fp32 accumulate; epilogue scales by dinv and
// stores hs16.
// Fragment layouts (mfma_f32_16x16x32_f16):
//   A: lane l holds A[l&15][s*32 + (l>>4)*8 + j]
//   B: lane l holds B[s*32 + (l>>4)*8 + j][c*16 + (l&15)]
//   D: lane l, reg r -> row (l>>4)*4+r, col l&15   (m89-verified)
__global__ __launch_bounds__(256) void k_gemm(const float* __restrict__ x,
                                              const float* __restrict__ w,
                                              const float* __restrict__ dinv,
                                              __half* __restrict__ hs16) {
    __shared__ _Float16 afr[4][4][64][8];  // [row-tile][s][lane][j] 16 KB
    __shared__ _Float16 bfr[4][4][64][8];  // [col-tile][s][lane][j] 16 KB
    const int t = threadIdx.x;
    const int row0 = blockIdx.x * 64;

    // --- stage B: w[128][64] fp32 -> fp16 frag order ---
    {
        const int col = t & 63, s = t >> 6;
        const int c = col >> 4, lb = col & 15;
#pragma unroll
        for (int g = 0; g < 4; g++) {
            union { _Float16 h[8]; uint4 u; } pk;
#pragma unroll
            for (int j = 0; j < 8; j++)
                pk.h[j] = (_Float16)w[(s * 32 + g * 8 + j) * 64 + col];
            *(uint4*)&bfr[c][s][lb | (g << 4)][0] = pk.u;
        }
    }
    // --- stage A: x rows row0..row0+63 fp32 -> fp16 frag order ---
    {
        const float4* xg = (const float4*)(x + (size_t)row0 * D_IN);
#pragma unroll
        for (int i = 0; i < 8; i++) {
            int flat = t + i * 256;        // float4 index in [64][32]
            int row = flat >> 5;
            int k4 = (flat & 31) << 2;     // k base (multiple of 4)
            float4 v = make_float4(0.f, 0.f, 0.f, 0.f);
            if (row0 + row < N_NODES) v = xg[flat];
            union { _Float16 h[4]; uint2 u; } pk;
            pk.h[0] = (_Float16)v.x; pk.h[1] = (_Float16)v.y;
            pk.h[2] = (_Float16)v.z; pk.h[3] = (_Float16)v.w;
            *(uint2*)&afr[row >> 4][k4 >> 5][(row & 15) | (((k4 >> 3) & 3) << 4)][k4 & 7] = pk.u;
        }
    }
    __syncthreads();

    const int wv = t >> 6, l = t & 63;
    f32x4 acc0 = {0.f, 0.f, 0.f, 0.f};
    f32x4 acc1 = {0.f, 0.f, 0.f, 0.f};
    f32x4 acc2 = {0.f, 0.f, 0.f, 0.f};
    f32x4 acc3 = {0.f, 0.f, 0.f, 0.f};
#pragma unroll
    for (int s = 0; s < 4; s++) {
        f16x8 a = *(const f16x8*)&afr[wv][s][l][0];
        f16x8 b0 = *(const f16x8*)&bfr[0][s][l][0];
        f16x8 b1 = *(const f16x8*)&bfr[1][s][l][0];
        f16x8 b2 = *(const f16x8*)&bfr[2][s][l][0];
        f16x8 b3 = *(const f16x8*)&bfr[3][s][l][0];
        acc0 = __builtin_amdgcn_mfma_f32_16x16x32_f16(a, b0, acc0, 0, 0, 0);
        acc1 = __builtin_amdgcn_mfma_f32_16x16x32_f16(a, b1, acc1, 0, 0, 0);
        acc2 = __builtin_amdgcn_mfma_f32_16x16x32_f16(a, b2, acc2, 0, 0, 0);
        acc3 = __builtin_amdgcn_mfma_f32_16x16x32_f16(a, b3, acc3, 0, 0, 0);
    }
    // epilogue: hs16[row][col] = fp16(acc * dinv[row])
    const int rbase = row0 + wv * 16 + ((l >> 4) << 2);
    const int cl = l & 15;
    _Float16* hsf = (_Float16*)hs16;
#pragma unroll
    for (int r = 0; r < 4; r++) {
        int row = rbase + r;
        if (row < N_NODES) {
            float dv = dinv[row];
            size_t base = (size_t)row * 64 + cl;
            hsf[base +  0] = (_Float16)(acc0[r] * dv);
            hsf[base + 16] = (_Float16)(acc1[r] * dv);
            hsf[base + 32] = (_Float16)(acc2[r] * dv);
            hsf[base + 48] = (_Float16)(acc3[r] * dv);
        }
    }
}

// One wave per node. Src indices are wave-uniform -> scalar (s_load) reads,
// no cross-lane ops. Each lane covers 2 columns (__half2, 4B load); the two
// 32-lane halves take the even/odd edge of each pair -> 256B per wave-load.
// fp32 accumulate, one shfl_xor(32) pair at the end, fused epilogue.
__global__ __launch_bounds__(256) void k_agg(const int* __restrict__ noff,
                                             const int* __restrict__ counts,
                                             const int* __restrict__ ssrc,
                                             const float* __restrict__ dinv,
                                             const __half2* __restrict__ hs2,
                                             const float* __restrict__ bias,
                                             float* __restrict__ out) {
    int t = blockIdx.x * 256 + threadIdx.x;
    int node = t >> 6, lane = t & 63;
    if (node >= N_NODES) return;
    const int half = lane >> 5;   // which edge of the pair
    const int hl = lane & 31;     // half2 column index (cols 2*hl, 2*hl+1)
    const int beg = __builtin_amdgcn_readfirstlane(noff[node]);
    const int cnt = __builtin_amdgcn_readfirstlane(counts[node]);
    float ax0 = 0.f, ay0 = 0.f, ax1 = 0.f, ay1 = 0.f;
    float ax2 = 0.f, ay2 = 0.f, ax3 = 0.f, ay3 = 0.f;
    int k = 0;
    for (; k + 8 <= cnt; k += 8) {
        int r0a = ssrc[beg + k + 0], r0b = ssrc[beg + k + 1];
        int r1a = ssrc[beg + k + 2], r1b = ssrc[beg + k + 3];
        int r2a = ssrc[beg + k + 4], r2b = ssrc[beg + k + 5];
        int r3a = ssrc[beg + k + 6], r3b = ssrc[beg + k + 7];
        int r0 = half ? r0b : r0a;
        int r1 = half ? r1b : r1a;
        int r2 = half ? r2b : r2a;
        int r3 = half ? r3b : r3a;
        float2 f0 = __half22float2(hs2[((unsigned)r0 << 5) + hl]);
        float2 f1 = __half22float2(hs2[((unsigned)r1 << 5) + hl]);
        float2 f2 = __half22float2(hs2[((unsigned)r2 << 5) + hl]);
        float2 f3 = __half22float2(hs2[((unsigned)r3 << 5) + hl]);
        ax0 += f0.x; ay0 += f0.y;
        ax1 += f1.x; ay1 += f1.y;
        ax2 += f2.x; ay2 += f2.y;
        ax3 += f3.x; ay3 += f3.y;
    }
    for (; k < cnt; k += 2) {
        int ra = ssrc[beg + k];
        int rb = (k + 1 < cnt) ? ssrc[beg + k + 1] : ra;
        int r = half ? rb : ra;
        float2 f = __half22float2(hs2[((unsigned)r << 5) + hl]);
        // when pair is incomplete, half 1 would duplicate edge ra -> mask it
        if (half == 0 || k + 1 < cnt) { ax0 += f.x; ay0 += f.y; }
    }
    float Ax = (ax0 + ax1) + (ax2 + ax3);
    float Ay = (ay0 + ay1) + (ay2 + ay3);
    Ax += __shfl_xor(Ax, 32);
    Ay += __shfl_xor(Ay, 32);
    float2 selfv = __half22float2(hs2[((unsigned)node << 5) + hl]);
    float dv = dinv[node];
    float2 bb = ((const float2*)bias)[hl];
    float vx = dv * (Ax + selfv.x) + bb.x;
    float vy = dv * (Ay + selfv.y) + bb.y;
    vx = vx > 0.f ? vx : 0.f;
    vy = vy > 0.f ? vy : 0.f;
    if (half == 0) {
        ((float2*)out)[((unsigned)node << 5) + hl] = make_float2(vx, vy);
    }
}

extern "C" void kernel_launch(void* const* d_in, const int* in_sizes, int n_in,
                              void* d_out, int out_size, void* d_ws, size_t ws_size,
                              hipStream_t stream) {
    const float* x    = (const float*)d_in[0];
    const int*   ei   = (const int*)d_in[1];   // [2][E] row-major
    const float* w    = (const float*)d_in[2];
    const float* bias = (const float*)d_in[3];
    float* out = (float*)d_out;

    int*    counts = (int*)d_ws;                         // N
    float*  dinv   = (float*)(counts + N_NODES);         // N
    __half* hs16   = (__half*)(dinv + N_NODES);          // N*64 halves = N*32 dwords
    int*    part   = (int*)((int*)(dinv + N_NODES) + N_NODES * 32);  // E
    int*    bsum   = part + N_EDGES;                     // 392
    int*    eoff   = bsum + 392;                         // NB+1
    int*    ecur   = eoff + 392;                         // NB
    int*    noff   = ecur + NB;                          // N

    const int* srcI = ei;
    const int* dstI = ei + N_EDGES;

    hipMemsetAsync(bsum, 0, NB * sizeof(int), stream);
    hipLaunchKernelGGL(k_bhist, dim3(NPART), dim3(256), 0, stream, dstI, bsum);
    hipLaunchKernelGGL(k_bscan, dim3(1), dim3(512), 0, stream, bsum, eoff, ecur);
    hipLaunchKernelGGL(k_part, dim3(NPART), dim3(256), 0, stream, srcI, dstI, ecur, part);
    hipLaunchKernelGGL(k_sort, dim3(NB), dim3(256), 0, stream, eoff, part, noff, counts, dinv);
    hipLaunchKernelGGL(k_gemm, dim3((N_NODES + 63) / 64), dim3(256), 0, stream, x, w, dinv, hs16);
    hipLaunchKernelGGL(k_agg, dim3((N_NODES * 64) / 256), dim3(256), 0, stream,
                       noff, counts, part, dinv, (const __half2*)hs16, bias, out);
}